// Round 5
// baseline (24991.937 us; speedup 1.0000x reference)
//
#include <hip/hip_runtime.h>

#define HH    51
#define T_SEQ 1024
#define T_TOT 1088
#define B_TOT 4096
#define MT    16
#define NTH   512

// ---- LDS layout (dwords) ----
#define P1O 0                    // layer-1 gate partials [4][16][64]
#define P2O (P1O + 4096)         // Whh2@h2_old partials [4][16][64]
#define H1O (P2O + 4096)         // h1 [16][64] (cols 51..63 stay 0)
#define H2O (H1O + 1024)         // h2 [16][64]
#define XBO (H2O + 1024)         // x double buffer [2][16][16]
#define OBO (XBO + 512)          // out staging [16][16]
#define XCO (OBO + 256)          // autoregressive x [16]
#define TOTF (XCO + 32)          // 11024 dw = 44 KiB

__device__ __forceinline__ float sigm(float v)  { return 1.f / (1.f + __expf(-v)); }
__device__ __forceinline__ float tanh_f(float v){ return 1.f - 2.f / (1.f + __expf(2.f * v)); }

__launch_bounds__(NTH, 1)
__global__ void lstm_seq_kernel(const float* __restrict__ x,
                                const float* __restrict__ Wih1,
                                const float* __restrict__ Whh1,
                                const float* __restrict__ bih1,
                                const float* __restrict__ bhh1,
                                const float* __restrict__ Wih2,
                                const float* __restrict__ Whh2,
                                const float* __restrict__ bih2,
                                const float* __restrict__ bhh2,
                                const float* __restrict__ Wlin,
                                const float* __restrict__ blin,
                                float* __restrict__ out)
{
  extern __shared__ float sm[];
  const int tid  = threadIdx.x;
  const int lane = tid & 63;
  const int w    = tid >> 6;          // wave 0..7
  const int bg0  = blockIdx.x * MT;
  const bool jv  = (lane < HH);
  const int  j   = lane;

  for (int i = tid; i < TOTF; i += NTH) sm[i] = 0.f;

  // ---- roles ----
  // w 0-1: Whh1 all 4 gates, rows w*8..w*8+7            (phase A)
  // w 2-3: Whh2 all 4 gates @ h2_old, rows (w-2)*8..+7  (phase A)
  // w 4-7: Wih2 all 4 gates, rows (w-4)*4..+3           (phase C, + act2/out)
  const int role  = (w < 2) ? 0 : (w < 4) ? 1 : 2;
  const int rows0 = (role == 0) ? w * 8 : (role == 1) ? (w - 2) * 8 : (w - 4) * 4;

  // ---- register-resident weight slice: 4 gates x 51 ----
  const float* Wsrc = (role == 0) ? Whh1 : (role == 1) ? Whh2 : Wih2;
  float Wr[4][51];
  #pragma unroll
  for (int g = 0; g < 4; ++g)
    #pragma unroll
    for (int k = 0; k < 51; ++k)
      Wr[g][k] = jv ? Wsrc[(g * HH + j) * HH + k] : 0.f;

  // role-dependent constants (union-allocated)
  // role 0: ea=Wih1 col, fb=bih1+bhh1 ; role 2: ea=bih2+bhh2, fb[0]=Wlin, fb[1]=blin
  float ea[4] = {0.f, 0.f, 0.f, 0.f};
  float fb[4] = {0.f, 0.f, 0.f, 0.f};
  if (role == 0) {
    #pragma unroll
    for (int g = 0; g < 4; ++g) {
      ea[g] = jv ? Wih1[g * HH + j] : 0.f;
      fb[g] = jv ? (bih1[g * HH + j] + bhh1[g * HH + j]) : 0.f;
    }
  } else if (role == 2) {
    #pragma unroll
    for (int g = 0; g < 4; ++g)
      ea[g] = jv ? (bih2[g * HH + j] + bhh2[g * HH + j]) : 0.f;
    fb[0] = jv ? Wlin[j] : 0.f;
    fb[1] = blin[0];
  }

  float c1[2] = {0.f, 0.f};                    // act1 rows 2w, 2w+1
  float c2[4] = {0.f, 0.f, 0.f, 0.f};          // role-2 rows rows0..rows0+3

  // x chunk 0
  if (tid < 256) {
    const int r = tid >> 4, tt = tid & 15;
    sm[XBO + r * 16 + tt] = x[(size_t)(bg0 + r) * T_SEQ + tt];
  }
  __syncthreads();

  #pragma unroll 1
  for (int t = 0; t < T_TOT; ++t) {
    const int tc = t & 15;
    // ================= phase A =================
    if (role == 2) {
      // x prefetch (waves 4-7 are idle in A): next 16-step chunk
      if (tc == 0 && (t + 16) < T_SEQ) {
        const int nt = t + 16;
        const int idx = (w - 4) * 64 + lane;   // 0..255
        const int r = idx >> 4, tt = idx & 15;
        sm[XBO + ((nt >> 4) & 1) * 256 + r * 16 + tt] =
            x[(size_t)(bg0 + r) * T_SEQ + nt + tt];
      }
    } else if (role == 0) {
      // layer-1 gates: 8 rows in 4 passes of 2
      const int xb = XBO + ((t >> 4) & 1) * 256;
      #pragma unroll
      for (int p = 0; p < 4; ++p) {
        const int r0p = rows0 + 2 * p;
        float acc[4][2];
        #pragma unroll
        for (int rr = 0; rr < 2; ++rr) {
          const float xv = (t < T_SEQ) ? sm[xb + (r0p + rr) * 16 + tc]
                                       : sm[XCO + r0p + rr];
          #pragma unroll
          for (int g = 0; g < 4; ++g) acc[g][rr] = fb[g] + ea[g] * xv;
        }
        #pragma unroll
        for (int c = 0; c < 13; ++c) {
          #pragma unroll
          for (int rr = 0; rr < 2; ++rr) {
            const float4 hv = *reinterpret_cast<const float4*>(&sm[H1O + (r0p + rr) * 64 + 4 * c]);
            const float hx[4] = {hv.x, hv.y, hv.z, hv.w};
            #pragma unroll
            for (int kk = 0; kk < 4; ++kk) {
              if (4 * c + kk < 51) {
                #pragma unroll
                for (int g = 0; g < 4; ++g)
                  acc[g][rr] += Wr[g][4 * c + kk] * hx[kk];
              }
            }
          }
        }
        #pragma unroll
        for (int g = 0; g < 4; ++g)
          #pragma unroll
          for (int rr = 0; rr < 2; ++rr)
            sm[P1O + (g * 16 + r0p + rr) * 64 + j] = acc[g][rr];
      }
    } else {  // role 1: Whh2 @ h2_old partials
      #pragma unroll
      for (int p = 0; p < 4; ++p) {
        const int r0p = rows0 + 2 * p;
        float acc[4][2] = {{0.f,0.f},{0.f,0.f},{0.f,0.f},{0.f,0.f}};
        #pragma unroll
        for (int c = 0; c < 13; ++c) {
          #pragma unroll
          for (int rr = 0; rr < 2; ++rr) {
            const float4 hv = *reinterpret_cast<const float4*>(&sm[H2O + (r0p + rr) * 64 + 4 * c]);
            const float hx[4] = {hv.x, hv.y, hv.z, hv.w};
            #pragma unroll
            for (int kk = 0; kk < 4; ++kk) {
              if (4 * c + kk < 51) {
                #pragma unroll
                for (int g = 0; g < 4; ++g)
                  acc[g][rr] += Wr[g][4 * c + kk] * hx[kk];
              }
            }
          }
        }
        #pragma unroll
        for (int g = 0; g < 4; ++g)
          #pragma unroll
          for (int rr = 0; rr < 2; ++rr)
            sm[P2O + (g * 16 + r0p + rr) * 64 + j] = acc[g][rr];
      }
    }
    __syncthreads();

    // ================= phase B: act1, rows 2w, 2w+1 =================
    {
      const int r0b = 2 * w;
      #pragma unroll
      for (int rr = 0; rr < 2; ++rr) {
        const int r = r0b + rr;
        const float g0 = sm[P1O + (0 * 16 + r) * 64 + j];
        const float g1 = sm[P1O + (1 * 16 + r) * 64 + j];
        const float g2 = sm[P1O + (2 * 16 + r) * 64 + j];
        const float g3 = sm[P1O + (3 * 16 + r) * 64 + j];
        const float cn = sigm(g1) * c1[rr] + sigm(g0) * tanh_f(g2);
        c1[rr] = cn;
        sm[H1O + r * 64 + j] = sigm(g3) * tanh_f(cn);  // 0 for lanes >= 51
      }
    }
    __syncthreads();

    // ================= phase C: layer-2 finish (waves 4-7) =================
    if (role == 2) {
      #pragma unroll
      for (int p = 0; p < 2; ++p) {
        const int r0p = rows0 + 2 * p;
        float acc[4][2];
        #pragma unroll
        for (int g = 0; g < 4; ++g)
          #pragma unroll
          for (int rr = 0; rr < 2; ++rr)
            acc[g][rr] = ea[g] + sm[P2O + (g * 16 + r0p + rr) * 64 + j];
        #pragma unroll
        for (int c = 0; c < 13; ++c) {
          #pragma unroll
          for (int rr = 0; rr < 2; ++rr) {
            const float4 hv = *reinterpret_cast<const float4*>(&sm[H1O + (r0p + rr) * 64 + 4 * c]);
            const float hx[4] = {hv.x, hv.y, hv.z, hv.w};
            #pragma unroll
            for (int kk = 0; kk < 4; ++kk) {
              if (4 * c + kk < 51) {
                #pragma unroll
                for (int g = 0; g < 4; ++g)
                  acc[g][rr] += Wr[g][4 * c + kk] * hx[kk];
              }
            }
          }
        }
        #pragma unroll
        for (int rr = 0; rr < 2; ++rr) {
          const int r = r0p + rr;
          const float cn = sigm(acc[1][rr]) * c2[2 * p + rr] + sigm(acc[0][rr]) * tanh_f(acc[2][rr]);
          c2[2 * p + rr] = cn;
          const float h2 = sigm(acc[3][rr]) * tanh_f(cn);
          sm[H2O + r * 64 + j] = h2;                   // 0 for lanes >= 51
          float po = fb[0] * h2;
          #pragma unroll
          for (int m = 32; m >= 1; m >>= 1) po += __shfl_xor(po, m, 64);
          if (lane == 0) {
            const float ov = po + fb[1];
            sm[OBO + r * 16 + tc] = ov;
            sm[XCO + r] = ov;                          // next-step x when t >= 1024
          }
        }
      }
      // flush this wave's 4 rows every 16 steps (coalesced 16-dword runs)
      if (tc == 15) {
        const int rl = lane >> 4, tt = lane & 15;
        const int r = rows0 + rl;
        out[(size_t)(bg0 + r) * T_TOT + (t - 15) + tt] = sm[OBO + r * 16 + tt];
      }
    }
    __syncthreads();
  }
}

extern "C" void kernel_launch(void* const* d_in, const int* in_sizes, int n_in,
                              void* d_out, int out_size, void* d_ws, size_t ws_size,
                              hipStream_t stream) {
  const float* x    = (const float*)d_in[0];
  const float* Wih1 = (const float*)d_in[1];
  const float* Whh1 = (const float*)d_in[2];
  const float* bih1 = (const float*)d_in[3];
  const float* bhh1 = (const float*)d_in[4];
  const float* Wih2 = (const float*)d_in[5];
  const float* Whh2 = (const float*)d_in[6];
  const float* bih2 = (const float*)d_in[7];
  const float* bhh2 = (const float*)d_in[8];
  const float* Wlin = (const float*)d_in[9];
  const float* blin = (const float*)d_in[10];
  float* out = (float*)d_out;

  const size_t smem = (size_t)TOTF * sizeof(float);   // 44 KiB
  (void)hipFuncSetAttribute((const void*)lstm_seq_kernel,
                            hipFuncAttributeMaxDynamicSharedMemorySize, (int)smem);

  lstm_seq_kernel<<<B_TOT / MT, NTH, smem, stream>>>(
      x, Wih1, Whh1, bih1, bhh1, Wih2, Whh2, bih2, bhh2, Wlin, blin, out);
}

// Round 6
// 2374.198 us; speedup vs baseline: 10.5265x; 10.5265x over previous
//
#include <hip/hip_runtime.h>

#define HH    51
#define T_SEQ 1024
#define T_TOT 1088
#define B_TOT 4096
#define MT    16
#define NTH   512

typedef __attribute__((ext_vector_type(8))) short bf8_t;   // 8 bf16 (4 VGPRs)
typedef __attribute__((ext_vector_type(4))) float f32x4;   // MFMA C/D

// ---- LDS layout (bytes) ----
// h buffers: [2 parity][16 rows][128 B] bf16, XOR-swizzled rows
#define H1H_O 0
#define H1L_O 4096
#define H2H_O 8192
#define H2L_O 12288
#define XB_O  16384   // float [2][16][16]
#define OB_O  18432   // float [2][16][16]
#define PT_O  20480   // float [2][4][16]
#define SM_SZ 20992

__device__ __forceinline__ short f2bf(float f) {            // fp32 -> bf16 RNE
  unsigned u = __builtin_bit_cast(unsigned, f);
  u += 0x7fffu + ((u >> 16) & 1u);
  return (short)(u >> 16);
}
__device__ __forceinline__ float bf2f(short s) {
  unsigned u = ((unsigned)(unsigned short)s) << 16;
  return __builtin_bit_cast(float, u);
}
__device__ __forceinline__ float sigm(float v)  { return 1.f / (1.f + __expf(-v)); }
__device__ __forceinline__ float tanh_f(float v){ return 1.f - 2.f / (1.f + __expf(2.f * v)); }

__device__ __forceinline__ f32x4 MFMA(bf8_t a, bf8_t b, f32x4 c) {
  return __builtin_amdgcn_mfma_f32_16x16x32_bf16(a, b, c, 0, 0, 0);
}
// A-frag read: row = batch row (lane&15), off = k-block byte offset (16B-aligned)
__device__ __forceinline__ bf8_t ldA(const char* base, int row, int off) {
  off ^= ((row & 7) << 4);
  return *reinterpret_cast<const bf8_t*>(base + row * 128 + off);
}
__device__ __forceinline__ void st16(char* base, int row, int boff, short v) {
  boff ^= ((row & 7) << 4);
  *reinterpret_cast<short*>(base + row * 128 + boff) = v;
}

__global__ __launch_bounds__(NTH, 2)
void lstm_mfma_kernel(const float* __restrict__ x,
                      const float* __restrict__ Wih1, const float* __restrict__ Whh1,
                      const float* __restrict__ bih1, const float* __restrict__ bhh1,
                      const float* __restrict__ Wih2, const float* __restrict__ Whh2,
                      const float* __restrict__ bih2, const float* __restrict__ bhh2,
                      const float* __restrict__ Wlin, const float* __restrict__ blin,
                      float* __restrict__ out)
{
  extern __shared__ char smc[];
  float* smf = (float*)smc;
  const int tid  = threadIdx.x;
  const int lane = tid & 63;
  const int w    = tid >> 6;
  const int cl   = lane & 15;         // A-row (batch) for loads / C-col (unit) for results
  const int gr   = lane >> 4;         // lane group
  const int rng  = w & 3;             // unit range 0..3 (units 16*rng..16*rng+15)
  const bool isL2 = (w >= 4);
  const int jo   = rng * 16 + cl;     // output unit of this lane's C-column
  const bool jv  = (jo < HH);
  const int bg0  = blockIdx.x * MT;

  for (int i = tid; i < SM_SZ / 4; i += NTH) smf[i] = 0.f;

  // ---- B-fragments (weights, bf16 hi/lo) in registers ----
  // k̂ map (same for A and B, so any HW k-permutation cancels): k̂ = 8*gr + s
  // W03 (layer1): kb 0..1 over Whh1 columns.  W47: kb 0..1 = Wih2 (h1 in), kb 2..3 = Whh2 (h2 in)
  bf8_t Bh[4][4], Bl[4][4];
  #pragma unroll
  for (int g = 0; g < 4; ++g) {
    #pragma unroll
    for (int kb = 0; kb < 4; ++kb) {
      bf8_t vh, vl;
      const bool dead = (!isL2 && kb >= 2);
      const float* Wsrc = isL2 ? (kb < 2 ? Wih2 : Whh2) : Whh1;
      const int kbase = (kb & 1) * 32;
      #pragma unroll
      for (int s = 0; s < 8; ++s) {
        const int ku = kbase + gr * 8 + s;
        float v = (!dead && jv && ku < HH) ? Wsrc[(g * HH + jo) * HH + ku] : 0.f;
        const short hh = f2bf(v);
        vh[s] = hh;
        vl[s] = f2bf(v - bf2f(hh));
      }
      Bh[g][kb] = vh; Bl[g][kb] = vl;
    }
  }
  // per-lane constants
  float cbv[4], wih1v[4];
  #pragma unroll
  for (int g = 0; g < 4; ++g) {
    cbv[g]   = jv ? (isL2 ? (bih2[g*HH+jo] + bhh2[g*HH+jo])
                          : (bih1[g*HH+jo] + bhh1[g*HH+jo])) : 0.f;
    wih1v[g] = (jv && !isL2) ? Wih1[g*HH+jo] : 0.f;
  }
  const float wlv = (jv && isL2) ? Wlin[jo] : 0.f;
  const float bl  = blin[0];
  float cst[4] = {0.f, 0.f, 0.f, 0.f};          // c1 (W03) / c2 (W47) per (jo, 4 rows)

  // ---- helpers ----
  auto do_l1 = [&](int t, const float xv[4]) {
    const int p = t & 1;
    const char* RH = smc + H1H_O + (p ^ 1) * 2048;
    const char* RL = smc + H1L_O + (p ^ 1) * 2048;
    bf8_t a0 = ldA(RH, cl, gr*16), a1 = ldA(RH, cl, 64 + gr*16);
    bf8_t l0 = ldA(RL, cl, gr*16), l1 = ldA(RL, cl, 64 + gr*16);
    f32x4 acc[4];
    #pragma unroll
    for (int g = 0; g < 4; ++g) {
      f32x4 a = {cbv[g], cbv[g], cbv[g], cbv[g]};
      a = MFMA(a0, Bh[g][0], a); a = MFMA(a1, Bh[g][1], a);   // hh·Wh
      a = MFMA(l0, Bh[g][0], a); a = MFMA(l1, Bh[g][1], a);   // hl·Wh
      a = MFMA(a0, Bl[g][0], a); a = MFMA(a1, Bl[g][1], a);   // hh·Wl
      acc[g] = a;
    }
    #pragma unroll
    for (int g = 0; g < 4; ++g)
      #pragma unroll
      for (int r = 0; r < 4; ++r) acc[g][r] += wih1v[g] * xv[r];   // exact fp32 x-term
    char* WH = smc + H1H_O + p * 2048;
    char* WL = smc + H1L_O + p * 2048;
    #pragma unroll
    for (int r = 0; r < 4; ++r) {
      const float cn = sigm(acc[1][r]) * cst[r] + sigm(acc[0][r]) * tanh_f(acc[2][r]);
      cst[r] = cn;
      const float hv = sigm(acc[3][r]) * tanh_f(cn);
      if (jv) {
        const int row = gr * 4 + r;
        const short hh = f2bf(hv);
        st16(WH, row, 2 * jo, hh);
        st16(WL, row, 2 * jo, f2bf(hv - bf2f(hh)));
      }
    }
  };

  auto do_l2 = [&](int tau) {
    const int q = tau & 1;
    const char* R1H = smc + H1H_O + q * 2048,       *R1L = smc + H1L_O + q * 2048;
    const char* R2H = smc + H2H_O + (q ^ 1) * 2048, *R2L = smc + H2L_O + (q ^ 1) * 2048;
    bf8_t a[4], al[4];
    a[0]  = ldA(R1H, cl, gr*16); a[1]  = ldA(R1H, cl, 64 + gr*16);
    a[2]  = ldA(R2H, cl, gr*16); a[3]  = ldA(R2H, cl, 64 + gr*16);
    al[0] = ldA(R1L, cl, gr*16); al[1] = ldA(R1L, cl, 64 + gr*16);
    al[2] = ldA(R2L, cl, gr*16); al[3] = ldA(R2L, cl, 64 + gr*16);
    f32x4 acc[4];
    #pragma unroll
    for (int g = 0; g < 4; ++g) {
      f32x4 ac = {cbv[g], cbv[g], cbv[g], cbv[g]};
      #pragma unroll
      for (int kb = 0; kb < 4; ++kb) ac = MFMA(a[kb],  Bh[g][kb], ac);   // hh·Wh
      #pragma unroll
      for (int kb = 0; kb < 4; ++kb) ac = MFMA(al[kb], Bh[g][kb], ac);   // hl·Wh
      #pragma unroll
      for (int kb = 0; kb < 4; ++kb) ac = MFMA(a[kb],  Bl[g][kb], ac);   // hh·Wl
      acc[g] = ac;
    }
    char* WH = smc + H2H_O + q * 2048;
    char* WL = smc + H2L_O + q * 2048;
    float po[4];
    #pragma unroll
    for (int r = 0; r < 4; ++r) {
      const float cn = sigm(acc[1][r]) * cst[r] + sigm(acc[0][r]) * tanh_f(acc[2][r]);
      cst[r] = cn;
      const float hv = sigm(acc[3][r]) * tanh_f(cn);
      if (jv) {
        const int row = gr * 4 + r;
        const short hh = f2bf(hv);
        st16(WH, row, 2 * jo, hh);
        st16(WL, row, 2 * jo, f2bf(hv - bf2f(hh)));
      }
      po[r] = wlv * hv;
    }
    #pragma unroll
    for (int r = 0; r < 4; ++r) {
      #pragma unroll
      for (int m = 1; m < 16; m <<= 1) po[r] += __shfl_xor(po[r], m, 64);
    }
    if (cl == 0) {
      #pragma unroll
      for (int r = 0; r < 4; ++r)
        smf[PT_O/4 + q*64 + rng*16 + gr*4 + r] = po[r];
    }
  };

  auto finalize = [&](int tw, float ov[4]) {   // all-lane: out(tw) from partials
    const int q = tw & 1;
    #pragma unroll
    for (int r = 0; r < 4; ++r) {
      const int row = gr * 4 + r;
      ov[r] = smf[PT_O/4 + q*64 +  0 + row] + smf[PT_O/4 + q*64 + 16 + row]
            + smf[PT_O/4 + q*64 + 32 + row] + smf[PT_O/4 + q*64 + 48 + row] + bl;
    }
  };
  auto writeOB = [&](int tw, const float ov[4]) {   // call on w==0; lanes cl==0 write
    if (cl == 0) {
      const int po = (tw >> 4) & 1, cc = tw & 15;
      #pragma unroll
      for (int r = 0; r < 4; ++r)
        smf[OB_O/4 + po*256 + (gr*4 + r)*16 + cc] = ov[r];
    }
  };
  auto flushOB = [&](int tb) {   // w3: 256 coalesced stores of block tb..tb+15
    const int q = (tb >> 4) & 1;
    #pragma unroll
    for (int it = 0; it < 4; ++it) {
      const int idx = lane + 64 * it;
      const int r = idx >> 4, tt = idx & 15;
      out[(size_t)(bg0 + r) * T_TOT + tb + tt] = smf[OB_O/4 + q*256 + r*16 + tt];
    }
  };

  // stage x chunk 0
  __syncthreads();
  if (tid < 256) {
    const int r = tid >> 4, tt = tid & 15;
    smf[XB_O/4 + r*16 + tt] = x[(size_t)(bg0 + r) * T_SEQ + tt];
  }
  __syncthreads();

  // ======== merged pipeline: layer1(t) || layer2(t-1), one barrier/step ========
  #pragma unroll 1
  for (int t = 0; t < T_SEQ; ++t) {
    if (!isL2) {
      if (w == 0 && t >= 2) { float ov[4]; finalize(t - 2, ov); writeOB(t - 2, ov); }
      if ((w == 1 || w == 2) && (t & 15) == 0 && (t + 16) < T_SEQ) {
        const int nt = t + 16, par = (nt >> 4) & 1;
        #pragma unroll
        for (int it = 0; it < 2; ++it) {
          const int idx = (w - 1) * 128 + lane + 64 * it;
          const int r = idx >> 4, tt = idx & 15;
          smf[XB_O/4 + par*256 + r*16 + tt] = x[(size_t)(bg0 + r) * T_SEQ + nt + tt];
        }
      }
      if (w == 3 && (t & 15) == 9 && t >= 25) flushOB(((t - 2) & ~15) - 16);
      float xv[4];
      const int par = (t >> 4) & 1, cc = t & 15;
      #pragma unroll
      for (int r = 0; r < 4; ++r) xv[r] = smf[XB_O/4 + par*256 + (gr*4 + r)*16 + cc];
      do_l1(t, xv);
    } else {
      if (t >= 1) do_l2(t - 1);
    }
    __syncthreads();
  }
  // drain: layer2(1023) + finalize out(1022)
  if (isL2) do_l2(T_SEQ - 1);
  else if (w == 0) { float ov[4]; finalize(T_SEQ - 2, ov); writeOB(T_SEQ - 2, ov); }
  __syncthreads();

  // ======== autoregressive region: 2 serial phases/step ========
  #pragma unroll 1
  for (int t = T_SEQ; t < T_TOT; ++t) {
    if (!isL2) {
      float ov[4];
      finalize(t - 1, ov);                      // out(t-1) = x(t), all W03 waves
      if (w == 0) writeOB(t - 1, ov);
      if (w == 3 && (t & 15) == 8) flushOB(((t - 1) & ~15) - 16);
      do_l1(t, ov);
    }
    __syncthreads();
    if (isL2) do_l2(t);
    __syncthreads();
  }
  // epilogue: out(1087), final flush of block 1072..1087
  if (!isL2 && w == 0) { float ov[4]; finalize(T_TOT - 1, ov); writeOB(T_TOT - 1, ov); }
  __syncthreads();
  if (w == 3) flushOB(T_TOT - 16);
}

extern "C" void kernel_launch(void* const* d_in, const int* in_sizes, int n_in,
                              void* d_out, int out_size, void* d_ws, size_t ws_size,
                              hipStream_t stream) {
  const float* x    = (const float*)d_in[0];
  const float* Wih1 = (const float*)d_in[1];
  const float* Whh1 = (const float*)d_in[2];
  const float* bih1 = (const float*)d_in[3];
  const float* bhh1 = (const float*)d_in[4];
  const float* Wih2 = (const float*)d_in[5];
  const float* Whh2 = (const float*)d_in[6];
  const float* bih2 = (const float*)d_in[7];
  const float* bhh2 = (const float*)d_in[8];
  const float* Wlin = (const float*)d_in[9];
  const float* blin = (const float*)d_in[10];
  float* out = (float*)d_out;

  lstm_mfma_kernel<<<B_TOT / MT, NTH, SM_SZ, stream>>>(
      x, Wih1, Whh1, bih1, bhh1, Wih2, Whh2, bih2, bhh2, Wlin, blin, out);
}

// Round 7
// 1492.489 us; speedup vs baseline: 16.7451x; 1.5908x over previous
//
#include <hip/hip_runtime.h>

#define HH    51
#define T_SEQ 1024
#define T_TOT 1088
#define B_TOT 4096
#define MT    16
#define NTH   512

typedef __attribute__((ext_vector_type(8))) short bf8_t;   // 8 bf16 (4 VGPRs)
typedef __attribute__((ext_vector_type(4))) float f32x4;   // MFMA C/D

// ---- LDS layout (bytes) ----
#define H1H_O 0
#define H1L_O 4096
#define H2H_O 8192
#define H2L_O 12288
#define XB_O  16384   // float [2][16][16]
#define OB_O  18432   // float [2][16][16]
#define PT_O  20480   // float [2][4][16]
#define SM_SZ 20992

#define L2E 1.44269504088896f

#if __has_builtin(__builtin_amdgcn_exp2f)
#define FEXP2 __builtin_amdgcn_exp2f
#else
#define FEXP2 exp2f
#endif
#if __has_builtin(__builtin_amdgcn_rcpf)
#define FRCP __builtin_amdgcn_rcpf
#else
#define FRCP(v) (1.f / (v))
#endif

__device__ __forceinline__ short f2bf(float f) {            // RNE (setup only)
  unsigned u = __builtin_bit_cast(unsigned, f);
  u += 0x7fffu + ((u >> 16) & 1u);
  return (short)(u >> 16);
}
__device__ __forceinline__ float bf2f(short s) {
  unsigned u = ((unsigned)(unsigned short)s) << 16;
  return __builtin_bit_cast(float, u);
}
// lsig(v) = 1/(1+2^v).  sigma(x)=lsig(-L2E*x) ; tanh(x)=1-2*lsig(2*L2E*x)
__device__ __forceinline__ float lsig(float v) { return FRCP(1.f + FEXP2(v)); }

__device__ __forceinline__ f32x4 MFMA(bf8_t a, bf8_t b, f32x4 c) {
  return __builtin_amdgcn_mfma_f32_16x16x32_bf16(a, b, c, 0, 0, 0);
}
__device__ __forceinline__ bf8_t ldA(const char* base, int row, int off) {
  off ^= ((row & 7) << 4);
  return *reinterpret_cast<const bf8_t*>(base + row * 128 + off);
}
// truncation hi/lo split store (4 VALU): exact residual, err <= 2^-16 rel
__device__ __forceinline__ void sthl(char* WH, char* WL, int row, int boff, float v) {
  const int o = row * 128 + (boff ^ ((row & 7) << 4));
  const unsigned u = __builtin_bit_cast(unsigned, v);
  *reinterpret_cast<short*>(WH + o) = (short)(u >> 16);
  const float rem = v - __builtin_bit_cast(float, u & 0xffff0000u);
  *reinterpret_cast<short*>(WL + o) = (short)(__builtin_bit_cast(unsigned, rem) >> 16);
}

__global__ __launch_bounds__(NTH, 1)
void lstm_mfma_kernel(const float* __restrict__ x,
                      const float* __restrict__ Wih1, const float* __restrict__ Whh1,
                      const float* __restrict__ bih1, const float* __restrict__ bhh1,
                      const float* __restrict__ Wih2, const float* __restrict__ Whh2,
                      const float* __restrict__ bih2, const float* __restrict__ bhh2,
                      const float* __restrict__ Wlin, const float* __restrict__ blin,
                      float* __restrict__ out)
{
  extern __shared__ char smc[];
  float* smf = (float*)smc;
  const int tid  = threadIdx.x;
  const int lane = tid & 63;
  const int w    = tid >> 6;
  const int cl   = lane & 15;
  const int gr   = lane >> 4;
  const int rng  = w & 3;
  const bool isL2 = (w >= 4);
  const int jo   = rng * 16 + cl;
  const bool jv  = (jo < HH);
  const int bg0  = blockIdx.x * MT;

  for (int i = tid; i < SM_SZ / 4; i += NTH) smf[i] = 0.f;

  // gate-domain scales folded into weights/biases: i,f,o -> -L2E ; g -> +2*L2E
  const float gsc[4] = {-L2E, -L2E, 2.f * L2E, -L2E};

  // ---- B-fragments (weights, bf16 hi/lo, pre-scaled) in registers ----
  bf8_t Bh[4][4], Bl[4][4];
  #pragma unroll
  for (int g = 0; g < 4; ++g) {
    #pragma unroll
    for (int kb = 0; kb < 4; ++kb) {
      bf8_t vh, vl;
      const bool dead = (!isL2 && kb >= 2);
      const float* Wsrc = isL2 ? (kb < 2 ? Wih2 : Whh2) : Whh1;
      const int kbase = (kb & 1) * 32;
      #pragma unroll
      for (int s = 0; s < 8; ++s) {
        const int ku = kbase + gr * 8 + s;
        float v = (!dead && jv && ku < HH) ? Wsrc[(g * HH + jo) * HH + ku] * gsc[g] : 0.f;
        const short hh = f2bf(v);
        vh[s] = hh;
        vl[s] = f2bf(v - bf2f(hh));
      }
      Bh[g][kb] = vh; Bl[g][kb] = vl;
    }
  }
  float cbv[4], wih1v[4];
  #pragma unroll
  for (int g = 0; g < 4; ++g) {
    cbv[g]   = jv ? (isL2 ? (bih2[g*HH+jo] + bhh2[g*HH+jo])
                          : (bih1[g*HH+jo] + bhh1[g*HH+jo])) * gsc[g] : 0.f;
    wih1v[g] = (jv && !isL2) ? Wih1[g*HH+jo] * gsc[g] : 0.f;
  }
  const float wlv = (jv && isL2) ? Wlin[jo] : 0.f;
  const float bl  = blin[0];
  float cst[4] = {0.f, 0.f, 0.f, 0.f};

  auto act_h = [&](const f32x4 acc[4], int r) -> float {   // scaled-domain LSTM cell
    const float si = lsig(acc[0][r]);
    const float sf = lsig(acc[1][r]);
    const float tg = 1.f - 2.f * lsig(acc[2][r]);
    const float so = lsig(acc[3][r]);
    const float cn = sf * cst[r] + si * tg;
    cst[r] = cn;
    return so * (1.f - 2.f * lsig(cn * (2.f * L2E)));
  };

  auto do_l1 = [&](const int p, const float xv[4]) {
    const char* RH = smc + H1H_O + (p ^ 1) * 2048;
    const char* RL = smc + H1L_O + (p ^ 1) * 2048;
    bf8_t a0 = ldA(RH, cl, gr*16), a1 = ldA(RH, cl, 64 + gr*16);
    bf8_t l0 = ldA(RL, cl, gr*16), l1 = ldA(RL, cl, 64 + gr*16);
    f32x4 acc[4];
    #pragma unroll
    for (int g = 0; g < 4; ++g) {
      f32x4 a = {cbv[g], cbv[g], cbv[g], cbv[g]};
      a = MFMA(a0, Bh[g][0], a); a = MFMA(a1, Bh[g][1], a);
      a = MFMA(l0, Bh[g][0], a); a = MFMA(l1, Bh[g][1], a);
      a = MFMA(a0, Bl[g][0], a); a = MFMA(a1, Bl[g][1], a);
      acc[g] = a;
    }
    #pragma unroll
    for (int g = 0; g < 4; ++g)
      #pragma unroll
      for (int r = 0; r < 4; ++r) acc[g][r] += wih1v[g] * xv[r];
    char* WH = smc + H1H_O + p * 2048;
    char* WL = smc + H1L_O + p * 2048;
    #pragma unroll
    for (int r = 0; r < 4; ++r) {
      const float hv = act_h(acc, r);
      if (jv) sthl(WH, WL, gr * 4 + r, 2 * jo, hv);
    }
  };

  auto do_l2 = [&](const int q) {
    const char* R1H = smc + H1H_O + q * 2048,       *R1L = smc + H1L_O + q * 2048;
    const char* R2H = smc + H2H_O + (q ^ 1) * 2048, *R2L = smc + H2L_O + (q ^ 1) * 2048;
    bf8_t a[4], al[4];
    a[0]  = ldA(R1H, cl, gr*16); a[1]  = ldA(R1H, cl, 64 + gr*16);
    a[2]  = ldA(R2H, cl, gr*16); a[3]  = ldA(R2H, cl, 64 + gr*16);
    al[0] = ldA(R1L, cl, gr*16); al[1] = ldA(R1L, cl, 64 + gr*16);
    al[2] = ldA(R2L, cl, gr*16); al[3] = ldA(R2L, cl, 64 + gr*16);
    f32x4 acc[4];
    #pragma unroll
    for (int g = 0; g < 4; ++g) {
      f32x4 ac = {cbv[g], cbv[g], cbv[g], cbv[g]};
      #pragma unroll
      for (int kb = 0; kb < 4; ++kb) ac = MFMA(a[kb],  Bh[g][kb], ac);
      #pragma unroll
      for (int kb = 0; kb < 4; ++kb) ac = MFMA(al[kb], Bh[g][kb], ac);
      #pragma unroll
      for (int kb = 0; kb < 4; ++kb) ac = MFMA(a[kb],  Bl[g][kb], ac);
      acc[g] = ac;
    }
    char* WH = smc + H2H_O + q * 2048;
    char* WL = smc + H2L_O + q * 2048;
    float po[4];
    #pragma unroll
    for (int r = 0; r < 4; ++r) {
      const float hv = act_h(acc, r);
      if (jv) sthl(WH, WL, gr * 4 + r, 2 * jo, hv);
      po[r] = wlv * hv;
    }
    #pragma unroll
    for (int r = 0; r < 4; ++r) {
      #pragma unroll
      for (int m = 1; m < 16; m <<= 1) po[r] += __shfl_xor(po[r], m, 64);
    }
    if (cl == 0) {
      #pragma unroll
      for (int r = 0; r < 4; ++r)
        smf[PT_O/4 + q*64 + rng*16 + gr*4 + r] = po[r];
    }
  };

  auto finalize = [&](int tw, const int q, float ov[4]) {
    #pragma unroll
    for (int r = 0; r < 4; ++r) {
      const int row = gr * 4 + r;
      ov[r] = smf[PT_O/4 + q*64 +  0 + row] + smf[PT_O/4 + q*64 + 16 + row]
            + smf[PT_O/4 + q*64 + 32 + row] + smf[PT_O/4 + q*64 + 48 + row] + bl;
    }
    (void)tw;
  };
  auto writeOB = [&](int tw, const float ov[4]) {
    if (cl == 0) {
      const int po = (tw >> 4) & 1, cc = tw & 15;
      #pragma unroll
      for (int r = 0; r < 4; ++r)
        smf[OB_O/4 + po*256 + (gr*4 + r)*16 + cc] = ov[r];
    }
  };
  auto flushOB = [&](int tb) {
    const int q = (tb >> 4) & 1;
    #pragma unroll
    for (int it = 0; it < 4; ++it) {
      const int idx = lane + 64 * it;
      const int r = idx >> 4, tt = idx & 15;
      out[(size_t)(bg0 + r) * T_TOT + tb + tt] = smf[OB_O/4 + q*256 + r*16 + tt];
    }
  };

  __syncthreads();
  if (tid < 256) {
    const int r = tid >> 4, tt = tid & 15;
    smf[XB_O/4 + r*16 + tt] = x[(size_t)(bg0 + r) * T_SEQ + tt];
  }
  __syncthreads();

  auto main_step = [&](int t, const int p) {
    if (!isL2) {
      if (w == 0 && t >= 2) { float ov[4]; finalize(t - 2, p, ov); writeOB(t - 2, ov); }
      if ((w == 1 || w == 2) && (t & 15) == 0 && (t + 16) < T_SEQ) {
        const int nt = t + 16, par = (nt >> 4) & 1;
        #pragma unroll
        for (int it = 0; it < 2; ++it) {
          const int idx = (w - 1) * 128 + lane + 64 * it;
          const int r = idx >> 4, tt = idx & 15;
          smf[XB_O/4 + par*256 + r*16 + tt] = x[(size_t)(bg0 + r) * T_SEQ + nt + tt];
        }
      }
      if (w == 3 && (t & 15) == 9 && t >= 25) flushOB(((t - 2) & ~15) - 16);
      float xv[4];
      const int par = (t >> 4) & 1, cc = t & 15;
      #pragma unroll
      for (int r = 0; r < 4; ++r) xv[r] = smf[XB_O/4 + par*256 + (gr*4 + r)*16 + cc];
      do_l1(p, xv);
    } else {
      if (t >= 1) do_l2(p ^ 1);
    }
  };

  // ======== main pipeline: layer1(t) || layer2(t-1); parity is literal ========
  #pragma unroll 1
  for (int t = 0; t < T_SEQ; t += 2) {
    main_step(t, 0);
    __syncthreads();
    main_step(t + 1, 1);
    __syncthreads();
  }
  // drain
  if (isL2) do_l2(1);                                   // layer2(1023), q=1
  else if (w == 0) { float ov[4]; finalize(T_SEQ - 2, 0, ov); writeOB(T_SEQ - 2, ov); }
  __syncthreads();

  // ======== autoregressive region ========
  auto ar_step = [&](int t, const int p) {
    if (!isL2) {
      float ov[4];
      finalize(t - 1, p ^ 1, ov);
      if (w == 0) writeOB(t - 1, ov);
      if (w == 3 && (t & 15) == 8) flushOB(((t - 1) & ~15) - 16);
      do_l1(p, ov);
    }
    __syncthreads();
    if (isL2) do_l2(p);
    __syncthreads();
  };
  #pragma unroll 1
  for (int t = T_SEQ; t < T_TOT; t += 2) {
    ar_step(t, 0);
    ar_step(t + 1, 1);
  }
  if (!isL2 && w == 0) { float ov[4]; finalize(T_TOT - 1, 1, ov); writeOB(T_TOT - 1, ov); }
  __syncthreads();
  if (w == 3) flushOB(T_TOT - 16);
}

extern "C" void kernel_launch(void* const* d_in, const int* in_sizes, int n_in,
                              void* d_out, int out_size, void* d_ws, size_t ws_size,
                              hipStream_t stream) {
  const float* x    = (const float*)d_in[0];
  const float* Wih1 = (const float*)d_in[1];
  const float* Whh1 = (const float*)d_in[2];
  const float* bih1 = (const float*)d_in[3];
  const float* bhh1 = (const float*)d_in[4];
  const float* Wih2 = (const float*)d_in[5];
  const float* Whh2 = (const float*)d_in[6];
  const float* bih2 = (const float*)d_in[7];
  const float* bhh2 = (const float*)d_in[8];
  const float* Wlin = (const float*)d_in[9];
  const float* blin = (const float*)d_in[10];
  float* out = (float*)d_out;

  lstm_mfma_kernel<<<B_TOT / MT, NTH, SM_SZ, stream>>>(
      x, Wih1, Whh1, bih1, bhh1, Wih2, Whh2, bih2, bhh2, Wlin, blin, out);
}

// Round 8
// 1293.451 us; speedup vs baseline: 19.3219x; 1.1539x over previous
//
#include <hip/hip_runtime.h>

#define HH    51
#define T_SEQ 1024
#define T_TOT 1088
#define B_TOT 4096
#define MT    16
#define NTH   512

typedef __attribute__((ext_vector_type(8))) short bf8_t;   // 8 bf16 (4 VGPRs)
typedef __attribute__((ext_vector_type(4))) float f32x4;   // MFMA C/D

// ---- LDS layout (bytes) ----
#define H1H_O 0
#define H1L_O 4096
#define H2H_O 8192
#define H2L_O 12288
#define XB_O  16384   // float [2][16][16]
#define OB_O  18432   // float [2][16][16]
#define PT_O  20480   // float [2][4][16]
#define SM_SZ 20992

#define L2E 1.44269504088896f

#if __has_builtin(__builtin_amdgcn_exp2f)
#define FEXP2 __builtin_amdgcn_exp2f
#else
#define FEXP2 exp2f
#endif
#if __has_builtin(__builtin_amdgcn_rcpf)
#define FRCP __builtin_amdgcn_rcpf
#else
#define FRCP(v) (1.f / (v))
#endif

__device__ __forceinline__ short f2bf(float f) {            // RNE (setup only)
  unsigned u = __builtin_bit_cast(unsigned, f);
  u += 0x7fffu + ((u >> 16) & 1u);
  return (short)(u >> 16);
}
__device__ __forceinline__ float bf2f(short s) {
  unsigned u = ((unsigned)(unsigned short)s) << 16;
  return __builtin_bit_cast(float, u);
}
// lsig(v) = 1/(1+2^v).  sigma(x)=lsig(-L2E*x) ; tanh(x)=1-2*lsig(2*L2E*x)
__device__ __forceinline__ float lsig(float v) { return FRCP(1.f + FEXP2(v)); }

__device__ __forceinline__ f32x4 MFMA(bf8_t a, bf8_t b, f32x4 c) {
  return __builtin_amdgcn_mfma_f32_16x16x32_bf16(a, b, c, 0, 0, 0);
}
__device__ __forceinline__ bf8_t ldA(const char* base, int row, int off) {
  off ^= ((row & 7) << 4);
  return *reinterpret_cast<const bf8_t*>(base + row * 128 + off);
}
// truncation hi/lo split store (4 VALU): exact residual, err <= 2^-16 rel
__device__ __forceinline__ void sthl(char* WH, char* WL, int row, int boff, float v) {
  const int o = row * 128 + (boff ^ ((row & 7) << 4));
  const unsigned u = __builtin_bit_cast(unsigned, v);
  *reinterpret_cast<short*>(WH + o) = (short)(u >> 16);
  const float rem = v - __builtin_bit_cast(float, u & 0xffff0000u);
  *reinterpret_cast<short*>(WL + o) = (short)(__builtin_bit_cast(unsigned, rem) >> 16);
}

__global__ __launch_bounds__(NTH, 1)
void lstm_mfma_kernel(const float* __restrict__ x,
                      const float* __restrict__ Wih1, const float* __restrict__ Whh1,
                      const float* __restrict__ bih1, const float* __restrict__ bhh1,
                      const float* __restrict__ Wih2, const float* __restrict__ Whh2,
                      const float* __restrict__ bih2, const float* __restrict__ bhh2,
                      const float* __restrict__ Wlin, const float* __restrict__ blin,
                      float* __restrict__ out)
{
  extern __shared__ char smc[];
  float* smf = (float*)smc;
  const int tid  = threadIdx.x;
  const int lane = tid & 63;
  const int w    = tid >> 6;
  const int cl   = lane & 15;
  const int gr   = lane >> 4;
  const int rng  = w & 3;
  const bool isL2 = (w >= 4);
  const int jo   = rng * 16 + cl;
  const bool jv  = (jo < HH);
  const int bg0  = blockIdx.x * MT;

  for (int i = tid; i < SM_SZ / 4; i += NTH) smf[i] = 0.f;

  // gate-domain scales folded into weights/biases: i,f,o -> -L2E ; g -> +2*L2E
  const float gsc[4] = {-L2E, -L2E, 2.f * L2E, -L2E};

  // ---- B-fragments (weights, bf16 hi/lo, pre-scaled) in registers ----
  // k̂ = kb*32 + gr*8 + s.  L1: kb0-1 = Whh1, plus k=53 carries Wih1 (x slot).
  // L2: kb0-1 = Wih2, kb2-3 = Whh2 (k>=51 pads zero in each range).
  bf8_t Bh[4][4], Bl[4][4];
  #pragma unroll
  for (int g = 0; g < 4; ++g) {
    #pragma unroll
    for (int kb = 0; kb < 4; ++kb) {
      bf8_t vh, vl;
      const bool dead = (!isL2 && kb >= 2);
      const float* Wsrc = isL2 ? (kb < 2 ? Wih2 : Whh2) : Whh1;
      const int kbase = (kb & 1) * 32;
      #pragma unroll
      for (int s = 0; s < 8; ++s) {
        const int ku = kbase + gr * 8 + s;
        float v = (!dead && jv && ku < HH) ? Wsrc[(g * HH + jo) * HH + ku] * gsc[g] : 0.f;
        if (!isL2 && kb == 1 && ku == 53) v = jv ? Wih1[g * HH + jo] * gsc[g] : 0.f;
        const short hh = f2bf(v);
        vh[s] = hh;
        vl[s] = f2bf(v - bf2f(hh));
      }
      Bh[g][kb] = vh; Bl[g][kb] = vl;
    }
  }
  // Wlin B-fragments for the MFMA output projection (used by wave 4 only):
  // col 0 = Wlin hi, col 1 = Wlin lo (unscaled), over k of the h2 ranges.
  bf8_t Bo[2];
  #pragma unroll
  for (int kb = 0; kb < 2; ++kb) {
    bf8_t v;
    #pragma unroll
    for (int s = 0; s < 8; ++s) {
      const int ku = kb * 32 + gr * 8 + s;
      float wv = (ku < HH) ? Wlin[ku] : 0.f;
      const short hh = f2bf(wv);
      v[s] = (cl == 0) ? hh : (cl == 1) ? f2bf(wv - bf2f(hh)) : (short)0;
    }
    Bo[kb] = v;
  }
  float cbv[4], wih1v[4];
  #pragma unroll
  for (int g = 0; g < 4; ++g) {
    cbv[g]   = jv ? (isL2 ? (bih2[g*HH+jo] + bhh2[g*HH+jo])
                          : (bih1[g*HH+jo] + bhh1[g*HH+jo])) * gsc[g] : 0.f;
    wih1v[g] = (jv && !isL2) ? Wih1[g*HH+jo] * gsc[g] : 0.f;
  }
  const float wlv = (jv && isL2) ? Wlin[jo] : 0.f;
  const float bl  = blin[0];
  float cst[4] = {0.f, 0.f, 0.f, 0.f};

  auto act_h = [&](const f32x4 acc[4], int r) -> float {   // scaled-domain LSTM cell
    const float si = lsig(acc[0][r]);
    const float sf = lsig(acc[1][r]);
    const float tg = 1.f - 2.f * lsig(acc[2][r]);
    const float so = lsig(acc[3][r]);
    const float cn = sf * cst[r] + si * tg;
    cst[r] = cn;
    return so * (1.f - 2.f * lsig(cn * (2.f * L2E)));
  };

  auto writeOB = [&](int tw, const float ov[4]) {
    if (cl == 0) {
      const int po = (tw >> 4) & 1, cc = tw & 15;
      #pragma unroll
      for (int r = 0; r < 4; ++r)
        smf[OB_O/4 + po*256 + (gr*4 + r)*16 + cc] = ov[r];
    }
  };

  // xv == nullptr -> main phase (x comes in via k=53 of the A fragments)
  auto do_l1 = [&](const int p, const float* xv, const int t) {
    const char* RH = smc + H1H_O + (p ^ 1) * 2048;
    const char* RL = smc + H1L_O + (p ^ 1) * 2048;
    bf8_t a0 = ldA(RH, cl, gr*16), a1 = ldA(RH, cl, 64 + gr*16);
    bf8_t l0 = ldA(RL, cl, gr*16), l1 = ldA(RL, cl, 64 + gr*16);
    f32x4 acc[4];
    __builtin_amdgcn_s_setprio(1);
    #pragma unroll
    for (int g = 0; g < 4; ++g) {
      f32x4 a = {cbv[g], cbv[g], cbv[g], cbv[g]};
      a = MFMA(a0, Bh[g][0], a); a = MFMA(a1, Bh[g][1], a);
      a = MFMA(l0, Bh[g][0], a); a = MFMA(l1, Bh[g][1], a);
      a = MFMA(a0, Bl[g][0], a); a = MFMA(a1, Bl[g][1], a);
      acc[g] = a;
    }
    __builtin_amdgcn_s_setprio(0);
    if (xv) {
      #pragma unroll
      for (int g = 0; g < 4; ++g)
        #pragma unroll
        for (int r = 0; r < 4; ++r) acc[g][r] += wih1v[g] * xv[r];
    }
    char* WH = smc + H1H_O + p * 2048;
    char* WL = smc + H1L_O + p * 2048;
    #pragma unroll
    for (int r = 0; r < 4; ++r) {
      const float hv = act_h(acc, r);
      if (jv) sthl(WH, WL, gr * 4 + r, 2 * jo, hv);
    }
    // wave 3 seeds x(t+1) into k=53 of the buffer being written this step
    if (!xv && rng == 3 && (t + 1) < T_SEQ) {
      if (lane < 16) {
        const float xn = smf[XB_O/4 + (((t+1) >> 4) & 1) * 256 + lane * 16 + ((t+1) & 15)];
        sthl(WH, WL, lane, 2 * 53, xn);
      }
    }
  };

  auto do_l2 = [&](const int q, const bool ar, const int tw) {
    const char* R1H = smc + H1H_O + q * 2048,       *R1L = smc + H1L_O + q * 2048;
    const char* R2H = smc + H2H_O + (q ^ 1) * 2048, *R2L = smc + H2L_O + (q ^ 1) * 2048;
    bf8_t a[4], al[4];
    a[0]  = ldA(R1H, cl, gr*16); a[1]  = ldA(R1H, cl, 64 + gr*16);
    a[2]  = ldA(R2H, cl, gr*16); a[3]  = ldA(R2H, cl, 64 + gr*16);
    al[0] = ldA(R1L, cl, gr*16); al[1] = ldA(R1L, cl, 64 + gr*16);
    al[2] = ldA(R2L, cl, gr*16); al[3] = ldA(R2L, cl, 64 + gr*16);
    f32x4 acc[4];
    f32x4 d = {0.f, 0.f, 0.f, 0.f};
    __builtin_amdgcn_s_setprio(1);
    #pragma unroll
    for (int g = 0; g < 4; ++g) {
      f32x4 ac = {cbv[g], cbv[g], cbv[g], cbv[g]};
      #pragma unroll
      for (int kb = 0; kb < 4; ++kb) ac = MFMA(a[kb],  Bh[g][kb], ac);
      #pragma unroll
      for (int kb = 0; kb < 4; ++kb) ac = MFMA(al[kb], Bh[g][kb], ac);
      #pragma unroll
      for (int kb = 0; kb < 4; ++kb) ac = MFMA(a[kb],  Bl[g][kb], ac);
      acc[g] = ac;
    }
    if (!ar && rng == 0) {           // out(tw) = h2(tw) . Wlin  (4 extra MFMAs, w4)
      d = MFMA(a[3], Bo[1], d); d = MFMA(a[2], Bo[0], d);
      d = MFMA(al[3], Bo[1], d); d = MFMA(al[2], Bo[0], d);
    }
    __builtin_amdgcn_s_setprio(0);
    char* WH = smc + H2H_O + q * 2048;
    char* WL = smc + H2L_O + q * 2048;
    float po[4];
    #pragma unroll
    for (int r = 0; r < 4; ++r) {
      const float hv = act_h(acc, r);
      if (jv) sthl(WH, WL, gr * 4 + r, 2 * jo, hv);
      po[r] = wlv * hv;
    }
    if (!ar) {
      if (rng == 0 && tw >= 0) {
        float ov[4];
        #pragma unroll
        for (int r = 0; r < 4; ++r) ov[r] = d[r] + __shfl_xor(d[r], 1, 64) + bl;
        writeOB(tw, ov);
      }
    } else {
      #pragma unroll
      for (int r = 0; r < 4; ++r) {
        #pragma unroll
        for (int m = 1; m < 16; m <<= 1) po[r] += __shfl_xor(po[r], m, 64);
      }
      if (cl == 0) {
        #pragma unroll
        for (int r = 0; r < 4; ++r)
          smf[PT_O/4 + q*64 + rng*16 + gr*4 + r] = po[r];
      }
    }
  };

  auto finalize = [&](const int q, float ov[4]) {
    #pragma unroll
    for (int r = 0; r < 4; ++r) {
      const int row = gr * 4 + r;
      ov[r] = smf[PT_O/4 + q*64 +  0 + row] + smf[PT_O/4 + q*64 + 16 + row]
            + smf[PT_O/4 + q*64 + 32 + row] + smf[PT_O/4 + q*64 + 48 + row] + bl;
    }
  };
  auto flushOB = [&](int tb) {
    const int q = (tb >> 4) & 1;
    #pragma unroll
    for (int it = 0; it < 4; ++it) {
      const int idx = lane + 64 * it;
      const int r = idx >> 4, tt = idx & 15;
      out[(size_t)(bg0 + r) * T_TOT + tb + tt] = smf[OB_O/4 + q*256 + r*16 + tt];
    }
  };

  __syncthreads();
  if (tid < 256) {
    const int r = tid >> 4, tt = tid & 15;
    smf[XB_O/4 + r*16 + tt] = x[(size_t)(bg0 + r) * T_SEQ + tt];
  }
  if (tid < 16)   // seed x(0) into k=53 of h1 parity-1 (read by do_l1(t=0))
    sthl(smc + H1H_O + 2048, smc + H1L_O + 2048, tid, 2 * 53,
         x[(size_t)(bg0 + tid) * T_SEQ]);
  __syncthreads();

  auto main_step = [&](int t, const int p) {
    if (!isL2) {
      if ((w == 1 || w == 2) && (t & 15) == 0 && (t + 16) < T_SEQ) {
        const int nt = t + 16, par = (nt >> 4) & 1;
        #pragma unroll
        for (int it = 0; it < 2; ++it) {
          const int idx = (w - 1) * 128 + lane + 64 * it;
          const int r = idx >> 4, tt = idx & 15;
          smf[XB_O/4 + par*256 + r*16 + tt] = x[(size_t)(bg0 + r) * T_SEQ + nt + tt];
        }
      }
      if (w == 3 && (t & 15) == 9 && t >= 25) flushOB(((t - 2) & ~15) - 16);
      do_l1(p, nullptr, t);
    } else {
      if (t >= 1) do_l2(p ^ 1, false, t - 2);
    }
  };

  // ======== main pipeline: layer1(t) || layer2(t-1); parity literal ========
  #pragma unroll 1
  for (int t = 0; t < T_SEQ; t += 2) {
    main_step(t, 0);
    __syncthreads();
    main_step(t + 1, 1);
    __syncthreads();
  }
  // ---- drain: layer2(1023) in AR mode (PT for out(1023)); out(1022) via MFMA;
  //      L1 side zeroes the stale k=53 x slots for the AR phase.
  if (isL2) {
    do_l2(1, true, -1);
    if (rng == 0) {                    // out(1022) from h2(1022) (parity 0)
      const char* RH = smc + H2H_O;
      const char* RL = smc + H2L_O;
      bf8_t a2 = ldA(RH, cl, gr*16), a3 = ldA(RH, cl, 64 + gr*16);
      bf8_t b2 = ldA(RL, cl, gr*16), b3 = ldA(RL, cl, 64 + gr*16);
      f32x4 d = {0.f, 0.f, 0.f, 0.f};
      d = MFMA(a3, Bo[1], d); d = MFMA(a2, Bo[0], d);
      d = MFMA(b3, Bo[1], d); d = MFMA(b2, Bo[0], d);
      float ov[4];
      #pragma unroll
      for (int r = 0; r < 4; ++r) ov[r] = d[r] + __shfl_xor(d[r], 1, 64) + bl;
      writeOB(1022, ov);
    }
  } else if (w == 3 && lane < 16) {
    sthl(smc + H1H_O,        smc + H1L_O,        lane, 2 * 53, 0.f);
    sthl(smc + H1H_O + 2048, smc + H1L_O + 2048, lane, 2 * 53, 0.f);
  }
  __syncthreads();

  // ======== autoregressive region: 2 serial phases/step (PT path) ========
  auto ar_step = [&](int t, const int p) {
    if (!isL2) {
      float ov[4];
      finalize(p ^ 1, ov);
      if (w == 0) writeOB(t - 1, ov);
      if (w == 3 && (t & 15) == 8) flushOB(((t - 1) & ~15) - 16);
      do_l1(p, ov, t);
    }
    __syncthreads();
    if (isL2) do_l2(p, true, -1);
    __syncthreads();
  };
  #pragma unroll 1
  for (int t = T_SEQ; t < T_TOT; t += 2) {
    ar_step(t, 0);
    ar_step(t + 1, 1);
  }
  if (!isL2 && w == 0) { float ov[4]; finalize(1, ov); writeOB(T_TOT - 1, ov); }
  __syncthreads();
  if (w == 3) flushOB(T_TOT - 16);
}

extern "C" void kernel_launch(void* const* d_in, const int* in_sizes, int n_in,
                              void* d_out, int out_size, void* d_ws, size_t ws_size,
                              hipStream_t stream) {
  const float* x    = (const float*)d_in[0];
  const float* Wih1 = (const float*)d_in[1];
  const float* Whh1 = (const float*)d_in[2];
  const float* bih1 = (const float*)d_in[3];
  const float* bhh1 = (const float*)d_in[4];
  const float* Wih2 = (const float*)d_in[5];
  const float* Whh2 = (const float*)d_in[6];
  const float* bih2 = (const float*)d_in[7];
  const float* bhh2 = (const float*)d_in[8];
  const float* Wlin = (const float*)d_in[9];
  const float* blin = (const float*)d_in[10];
  float* out = (float*)d_out;

  lstm_mfma_kernel<<<B_TOT / MT, NTH, SM_SZ, stream>>>(
      x, Wih1, Whh1, bih1, bhh1, Wih2, Whh2, bih2, bhh2, Wlin, blin, out);
}